// Round 6
// baseline (2544.071 us; speedup 1.0000x reference)
//
#include <hip/hip_runtime.h>
#include <hip/hip_bf16.h>

#define Bb 64
#define Tt 256
#define Ii 256
#define Hh 512
#define Cc 1000
#define NSL 32  // slices (blocks) per layer
#define ND 16   // h dims per block
#define RD 4    // xg LDS ring depth

typedef float f4 __attribute__((ext_vector_type(4)));
typedef short s8 __attribute__((ext_vector_type(8)));
typedef unsigned long long u64;

__device__ __forceinline__ unsigned short f2bf(float f) {
  union { float f; unsigned u; } v; v.f = f;
  return (unsigned short)((v.u + 0x7FFFu + ((v.u >> 16) & 1u)) >> 16);
}
__device__ __forceinline__ float sigf(float x) {
  return __builtin_amdgcn_rcpf(1.f + __expf(-x));
}
__device__ __forceinline__ float tanhs(float x) {
  float ax = fabsf(x);
  float e = __expf(-2.f * ax);
  float r = (1.f - e) * __builtin_amdgcn_rcpf(1.f + e);
  return copysignf(r, x);
}

struct P5 {
  const float* x;
  const float* Whh[3];
  const float* bih[3]; const float* bhh[3];
  const unsigned short* wihb;  // pre-swizzled bf16 Wih fragments
  unsigned short* y[3];
  unsigned* fl;  // [3][NSL][4] monotonic (t+1), spread x16 u32
};

__global__ void zero_flags(unsigned* f) {
  for (int i = threadIdx.x; i < 3 * NSL * 4 * 16; i += 256) f[i] = 0;
}

__global__ void bias_init_kernel(const float* __restrict__ fcb, float* __restrict__ out) {
  int i = blockIdx.x * 256 + threadIdx.x;
  if (i < Bb * Cc) out[i] = fcb[i % Cc];
}

// Pre-swizzle Wih (fp32 -> bf16) into per-lane MFMA A-fragment order:
// flat group g = (((s*4+tt)*kcN+kc)*16+c)*4+q  -> 8 contiguous bf16.
__global__ void prep_wih(const float* __restrict__ w0, const float* __restrict__ w1,
                         const float* __restrict__ w2, unsigned short* __restrict__ dst) {
  int g = blockIdx.x * 256 + threadIdx.x;  // 327680 total groups
  const float* src; int kcN; size_t doff;
  if (g < 65536) { src = w0; kcN = 8; doff = 0; }
  else if (g < 65536 + 131072) { g -= 65536; src = w1; kcN = 16; doff = 524288; }
  else { g -= 65536 + 131072; src = w2; kcN = 16; doff = 524288 + 1048576; }
  int q = g & 3, c = (g >> 2) & 15;
  int rest = g >> 6;
  int kc = rest % kcN; rest /= kcN;
  int tt = rest & 3, s = rest >> 2;
  int K = kcN * 32;
  int j = (c & 3) * Hh + s * ND + 4 * tt + (c >> 2);
  const float* sp = src + (size_t)j * K + kc * 32 + 8 * q;
  s8 tv;
#pragma unroll
  for (int e = 0; e < 8; ++e) tv[e] = (short)f2bf(sp[e]);
  int gg = ((((s * 4 + tt) * kcN + kc) * 16 + c) * 4 + q);
  *(s8*)(dst + doff + (size_t)gg * 8) = tv;
}

// 96 blocks = 3 layers x 32 slices (16 dims). 512 threads: waves 0-3 recurrent
// (wave w owns batches 16w..16w+15), waves 4-7 input-GEMM producers feeding a
// 4-deep LDS xg ring (fp32 gate pre-activations incl. bias). No __syncthreads
// in the t-loop; cross-block sync = R4 flag protocol (sc1 h stores + flags).
__launch_bounds__(512, 1)
__global__ void lstm_kernel(P5 p) {
  const int bid = blockIdx.x;
  const int L = bid >> 5;
  const int s = bid & 31;
  const int n0 = s * ND;
  const int tid = threadIdx.x;
  const int lane = tid & 63;
  const int wv = tid >> 6;
  const int q = lane >> 4;
  const int c = lane & 15;
  const bool isrec = wv < 4;
  const int w = wv & 3;
  const int b = 16 * w + c;

  __shared__ unsigned short Whl[64 * 512];        // 64 KB, swizzled
  __shared__ float xg[RD * 4 * 16 * 68];          // 68 KB ring (+pad vs conflicts)
  __shared__ unsigned short hstage[4][16][16];    // 2 KB repack
  __shared__ unsigned xgrdy[RD][4];               // slot written: t+1
  __shared__ unsigned xgdone[RD][4];              // slot consumed: t+1

  if (tid < RD * 4) { xgrdy[tid >> 2][tid & 3] = 0; xgdone[tid >> 2][tid & 3] = 0; }

  {  // stage Whh slice (64 gate-rows x 512) fp32->bf16 swizzled
    const float* src = p.Whh[L];
    for (int idx = tid; idx < 64 * 64; idx += 512) {
      int r = idx >> 6, kk = (idx & 63) << 3;
      int rr = r & 15, tt = r >> 4;
      int j = (rr & 3) * Hh + n0 + 4 * tt + (rr >> 2);
      const float* sr = src + (size_t)j * Hh + kk;
      s8 tv;
#pragma unroll
      for (int e = 0; e < 8; ++e) tv[e] = (short)f2bf(sr[e]);
      int byt = ((r * 512 + kk) * 2) ^ ((r & 7) << 4);
      *(s8*)((char*)Whl + byt) = tv;
    }
  }
  __syncthreads();

  unsigned short* yl = p.y[L];

  if (isrec) {
    float cst[4] = {0.f, 0.f, 0.f, 0.f};
    const int aswz = (c & 7) << 4;
    for (int t = 0; t < Tt; ++t) {
      const int slot = t & (RD - 1);
      // 1. xg ready? (LDS, steady-state instant)
      while (__hip_atomic_load(&xgrdy[slot][w], __ATOMIC_RELAXED,
                               __HIP_MEMORY_SCOPE_WORKGROUP) < (unsigned)(t + 1))
        __builtin_amdgcn_s_sleep(1);
      f4 acc[4];
      {
        const float* xb = &xg[slot * 4352 + w * 1088 + c * 68];
#pragma unroll
        for (int tt = 0; tt < 4; ++tt) acc[tt] = *(const f4*)(xb + tt * 16 + q * 4);
      }
      asm volatile("s_waitcnt lgkmcnt(0)" ::: "memory");
      __builtin_amdgcn_sched_barrier(0);
      if (lane == 0)
        __hip_atomic_store(&xgdone[slot][w], (unsigned)(t + 1), __ATOMIC_RELAXED,
                           __HIP_MEMORY_SCOPE_WORKGROUP);
      if (t > 0) {
        // 2. poll h[t-1] flags (32 producers, this wave index)
        bool ok;
        do {
          unsigned v = 0xFFFFFFFFu;
          if (lane < 32)
            v = __hip_atomic_load(p.fl + ((L * NSL + lane) * 4 + w) * 16, __ATOMIC_RELAXED,
                                  __HIP_MEMORY_SCOPE_AGENT);
          ok = __all(v >= (unsigned)t);
          if (!ok) __builtin_amdgcn_s_sleep(1);
        } while (!ok);
        asm volatile("" ::: "memory");
        // 3. load h B-frags + rec GEMM
        const unsigned short* hr = yl + ((size_t)b * Tt + (t - 1)) * Hh + 8 * q;
        s8 hb[16];
#pragma unroll
        for (int kc = 0; kc < 16; ++kc) hb[kc] = *(const s8*)(hr + kc * 32);
#pragma unroll
        for (int tt = 0; tt < 4; ++tt)
#pragma unroll
          for (int kc = 0; kc < 16; ++kc) {
            int byt = (((tt * 16 + c) * 512 + kc * 32 + 8 * q) * 2) ^ aswz;
            s8 wa = *(const s8*)((const char*)Whl + byt);
            acc[tt] = __builtin_amdgcn_mfma_f32_16x16x32_bf16(wa, hb[kc], acc[tt], 0, 0, 0);
          }
      }
      // 4. pointwise: lane (q,c) owns dims n0+4tt+q, gates {i,f,g,o}=acc[tt][0..3]
#pragma unroll
      for (int tt = 0; tt < 4; ++tt) {
        float ii = sigf(acc[tt][0]), ff = sigf(acc[tt][1]);
        float gg = tanhs(acc[tt][2]), oo = sigf(acc[tt][3]);
        cst[tt] = ff * cst[tt] + ii * gg;
        hstage[w][c][4 * tt + q] = f2bf(oo * tanhs(cst[tt]));
      }
      asm volatile("s_waitcnt lgkmcnt(0)" ::: "memory");
      __builtin_amdgcn_sched_barrier(0);
      // 5. repack + sc1 store (lane<32: batch=lane&15, half=lane>>4)
      if (lane < 32) {
        int bb = lane & 15, hf = lane >> 4;
        const u64* hp = (const u64*)&hstage[w][bb][8 * hf];
        u64 d0 = hp[0], d1 = hp[1];
        u64* dst = (u64*)(yl + ((size_t)(16 * w + bb) * Tt + t) * Hh + n0 + 8 * hf);
        __hip_atomic_store(dst, d0, __ATOMIC_RELAXED, __HIP_MEMORY_SCOPE_AGENT);
        __hip_atomic_store(dst + 1, d1, __ATOMIC_RELAXED, __HIP_MEMORY_SCOPE_AGENT);
      }
      asm volatile("s_waitcnt vmcnt(0)" ::: "memory");
      if (lane == 0)
        __hip_atomic_store(p.fl + ((L * NSL + s) * 4 + w) * 16, (unsigned)(t + 1),
                           __ATOMIC_RELAXED, __HIP_MEMORY_SCOPE_AGENT);
    }
  } else {
    // input producer: xg[slot] = bias + Wih @ input[t], up to RD ahead
    const unsigned short* ylow = (L > 0) ? p.y[L - 1] : (const unsigned short*)0;
    const int kcN = (L == 0) ? 8 : 16;
    const unsigned short* wb =
        p.wihb + ((L == 0) ? 0 : (L == 1) ? 524288 : (524288 + 1048576));
    const s8* wfrag = (const s8*)wb + ((size_t)s * 4 * kcN * 16 + c) * 4 + q;  // + (tt*kcN+kc)*64
    f4 bias[4];
#pragma unroll
    for (int tt = 0; tt < 4; ++tt)
#pragma unroll
      for (int g = 0; g < 4; ++g) {
        int bi = g * Hh + n0 + 4 * tt + q;
        bias[tt][g] = p.bih[L][bi] + p.bhh[L][bi];
      }
    for (int t = 0; t < Tt; ++t) {
      const int slot = t & (RD - 1);
      if (L > 0) {  // input y[t] available?
        bool ok;
        do {
          unsigned v = 0xFFFFFFFFu;
          if (lane < 32)
            v = __hip_atomic_load(p.fl + (((L - 1) * NSL + lane) * 4 + w) * 16,
                                  __ATOMIC_RELAXED, __HIP_MEMORY_SCOPE_AGENT);
          ok = __all(v >= (unsigned)(t + 1));
          if (!ok) __builtin_amdgcn_s_sleep(1);
        } while (!ok);
        asm volatile("" ::: "memory");
      }
      // ring slot free?
      while (t >= RD && __hip_atomic_load(&xgdone[slot][w], __ATOMIC_RELAXED,
                                          __HIP_MEMORY_SCOPE_WORKGROUP) < (unsigned)(t - RD + 1))
        __builtin_amdgcn_s_sleep(1);
      f4 acc[4];
#pragma unroll
      for (int tt = 0; tt < 4; ++tt) acc[tt] = bias[tt];
      if (L == 0) {
        const float* xr = p.x + ((size_t)b * Tt + t) * Ii + 8 * q;
#pragma unroll
        for (int kc = 0; kc < 8; ++kc) {
          f4 xa = *(const f4*)(xr + kc * 32);
          f4 xc = *(const f4*)(xr + kc * 32 + 4);
          s8 xb;
#pragma unroll
          for (int e = 0; e < 4; ++e) { xb[e] = (short)f2bf(xa[e]); xb[e + 4] = (short)f2bf(xc[e]); }
#pragma unroll
          for (int tt = 0; tt < 4; ++tt)
            acc[tt] = __builtin_amdgcn_mfma_f32_16x16x32_bf16(wfrag[(tt * 8 + kc) * 64], xb,
                                                              acc[tt], 0, 0, 0);
        }
      } else {
        const unsigned short* yr = ylow + ((size_t)b * Tt + t) * Hh + 8 * q;
        s8 yb[16];
#pragma unroll
        for (int kc = 0; kc < 16; ++kc) yb[kc] = *(const s8*)(yr + kc * 32);
#pragma unroll
        for (int tt = 0; tt < 4; ++tt)
#pragma unroll
          for (int kc = 0; kc < 16; ++kc)
            acc[tt] = __builtin_amdgcn_mfma_f32_16x16x32_bf16(wfrag[(tt * 16 + kc) * 64], yb[kc],
                                                              acc[tt], 0, 0, 0);
      }
      {
        float* xo = &xg[slot * 4352 + w * 1088 + c * 68];
#pragma unroll
        for (int tt = 0; tt < 4; ++tt) *(f4*)(xo + tt * 16 + q * 4) = acc[tt];
      }
      asm volatile("s_waitcnt lgkmcnt(0)" ::: "memory");
      __builtin_amdgcn_sched_barrier(0);
      if (lane == 0)
        __hip_atomic_store(&xgrdy[slot][w], (unsigned)(t + 1), __ATOMIC_RELAXED,
                           __HIP_MEMORY_SCOPE_WORKGROUP);
    }
  }
}

// out^T-tiled FC: D[c,b] += fc_w[c,k] * y2[b,k]; 32 c-tiles x 32 k-chunks, atomic f32 adds.
__launch_bounds__(256)
__global__ void fc_kernel(const float* __restrict__ w, const unsigned short* __restrict__ y2,
                          float* __restrict__ out) {
  const int ct = blockIdx.x & 31;
  const int kch = blockIdx.x >> 5;
  const int tid = threadIdx.x, lane = tid & 63, wvv = tid >> 6;
  const int b = wvv * 16 + (lane & 15);
  const int KT = Tt * Hh;  // 131072
  const int kbase = kch * 4096 + (lane >> 4) * 8;
  const int c0 = ct * 32 + (lane & 15);
  const int c1 = c0 + 16;
  const bool v0 = (c0 < Cc), v1 = (c1 < Cc);
  const float* w0 = w + (size_t)c0 * KT;
  const float* w1 = w + (size_t)c1 * KT;
  const unsigned short* yr = y2 + (size_t)b * KT;
  f4 a0 = {0.f, 0.f, 0.f, 0.f}, a1 = {0.f, 0.f, 0.f, 0.f};
  for (int kk = 0; kk < 4096; kk += 32) {
    const int k = kbase + kk;
    s8 bf = *(const s8*)(yr + k);
    s8 wa0 = {0, 0, 0, 0, 0, 0, 0, 0}, wa1 = {0, 0, 0, 0, 0, 0, 0, 0};
    if (v0) {
#pragma unroll
      for (int qq = 0; qq < 8; ++qq) wa0[qq] = (short)f2bf(w0[k + qq]);
    }
    if (v1) {
#pragma unroll
      for (int qq = 0; qq < 8; ++qq) wa1[qq] = (short)f2bf(w1[k + qq]);
    }
    a0 = __builtin_amdgcn_mfma_f32_16x16x32_bf16(wa0, bf, a0, 0, 0, 0);
    a1 = __builtin_amdgcn_mfma_f32_16x16x32_bf16(wa1, bf, a1, 0, 0, 0);
  }
  const int rr = (lane >> 4) * 4;
#pragma unroll
  for (int qq = 0; qq < 4; ++qq) {
    int ca = ct * 32 + rr + qq;
    if (ca < Cc) atomicAdd(out + (size_t)b * Cc + ca, a0[qq]);
    int cb2 = ca + 16;
    if (cb2 < Cc) atomicAdd(out + (size_t)b * Cc + cb2, a1[qq]);
  }
}

extern "C" void kernel_launch(void* const* d_in, const int* in_sizes, int n_in,
                              void* d_out, int out_size, void* d_ws, size_t ws_size,
                              hipStream_t stream) {
  P5 p;
  p.x = (const float*)d_in[0];
  const float* wih0 = (const float*)d_in[1];  p.Whh[0] = (const float*)d_in[2];
  p.bih[0] = (const float*)d_in[3];  p.bhh[0] = (const float*)d_in[4];
  const float* wih1 = (const float*)d_in[5];  p.Whh[1] = (const float*)d_in[6];
  p.bih[1] = (const float*)d_in[7];  p.bhh[1] = (const float*)d_in[8];
  const float* wih2 = (const float*)d_in[9];  p.Whh[2] = (const float*)d_in[10];
  p.bih[2] = (const float*)d_in[11]; p.bhh[2] = (const float*)d_in[12];
  const float* fcw = (const float*)d_in[13];
  const float* fcb = (const float*)d_in[14];

  char* ws = (char*)d_ws;
  p.fl = (unsigned*)ws;  // 24 KB spread flags
  const size_t ysz = (size_t)Bb * Tt * Hh;
  unsigned short* y0 = (unsigned short*)(ws + 32768);
  p.y[0] = y0;
  p.y[1] = y0 + ysz;
  p.y[2] = y0 + 2 * ysz;
  unsigned short* wihb = (unsigned short*)(ws + 32768 + 3 * ysz * 2);  // 5 MB
  p.wihb = wihb;

  zero_flags<<<1, 256, 0, stream>>>(p.fl);
  prep_wih<<<1280, 256, 0, stream>>>(wih0, wih1, wih2, wihb);
  bias_init_kernel<<<250, 256, 0, stream>>>(fcb, (float*)d_out);
  lstm_kernel<<<96, 512, 0, stream>>>(p);
  fc_kernel<<<1024, 256, 0, stream>>>(fcw, p.y[2], (float*)d_out);
}